// Round 1
// baseline (9444.959 us; speedup 1.0000x reference)
//
#include <hip/hip_runtime.h>

// Neural ODE (Dopri5, 64 steps) — D=2048 state, H=8192 hidden.
// Per stage: h = tanh(W1 @ yi + s*wt + b1);  k = -(W2 @ h + b2)
// All tableau vector algebra fused into k_mv2's epilogue.
// fp32 everywhere (round-1 baseline). Memory-bound on weight streaming;
// W1+W2 = 128 MB fits Infinity Cache (256 MB) -> L3-resident after warmup.

constexpr int D = 2048;
constexpr int H = 8192;
constexpr int NSTEPS = 64;

// dA[i][j] = Dopri5 A-tableau row i (used to build yi for stage i)
__constant__ float c_A[6][5] = {
    {0.f, 0.f, 0.f, 0.f, 0.f},
    {1.f/5.f, 0.f, 0.f, 0.f, 0.f},
    {3.f/40.f, 9.f/40.f, 0.f, 0.f, 0.f},
    {44.f/45.f, -56.f/15.f, 32.f/9.f, 0.f, 0.f},
    {19372.f/6561.f, -25360.f/2187.f, 64448.f/6561.f, -212.f/729.f, 0.f},
    {9017.f/3168.f, -355.f/33.f, 46732.f/5247.f, 49.f/176.f, -5103.f/18656.f},
};

__device__ __forceinline__ float waveReduce(float v) {
    #pragma unroll
    for (int off = 32; off; off >>= 1) v += __shfl_down(v, off, 64);
    return v;
}

// h[row] = tanh( dot(W1[row,:], yi) + s*wt[row] + b1[row] )
// grid = H/8 = 1024 blocks, 256 threads (4 waves). Each wave: 2 rows.
__global__ __launch_bounds__(256) void k_mv1(
    const float* __restrict__ W1, const float* __restrict__ wt,
    const float* __restrict__ b1, const float* __restrict__ yi,
    float* __restrict__ h, float s)
{
    __shared__ float4 ylds[D / 4];
    const int tid = threadIdx.x;
    const float4* y4 = (const float4*)yi;
    for (int i = tid; i < D / 4; i += 256) ylds[i] = y4[i];
    __syncthreads();

    const int wave = tid >> 6, lane = tid & 63;
    const int rowBase = blockIdx.x * 8;
    #pragma unroll
    for (int rr = 0; rr < 2; ++rr) {
        const int row = rowBase + wave * 2 + rr;
        const float4* w4 = (const float4*)(W1 + (size_t)row * D);
        float a0 = 0.f, a1 = 0.f;
        #pragma unroll
        for (int it = 0; it < D / 256; it += 2) {
            float4 w0 = w4[(it + 0) * 64 + lane];
            float4 v0 = ylds[(it + 0) * 64 + lane];
            float4 w1 = w4[(it + 1) * 64 + lane];
            float4 v1 = ylds[(it + 1) * 64 + lane];
            a0 = fmaf(w0.x, v0.x, a0); a0 = fmaf(w0.y, v0.y, a0);
            a0 = fmaf(w0.z, v0.z, a0); a0 = fmaf(w0.w, v0.w, a0);
            a1 = fmaf(w1.x, v1.x, a1); a1 = fmaf(w1.y, v1.y, a1);
            a1 = fmaf(w1.z, v1.z, a1); a1 = fmaf(w1.w, v1.w, a1);
        }
        float acc = waveReduce(a0 + a1);
        if (lane == 0) h[row] = tanhf(fmaf(s, wt[row], acc + b1[row]));
    }
}

// k[row] = -( dot(W2[row,:], h) + b2[row] )  plus fused tableau epilogue:
//   stage<5 : yi[row]  = y[row] + dt * sum_j A[stage+1][j] * k_j[row]
//   stage==5: y[row]  += dt * (B0 k0 + B2 k2 + B3 k3 + B4 k4 + B5 k5)[row]
// grid = D/4 = 512 blocks, 256 threads (4 waves). Each wave: 1 row.
__global__ __launch_bounds__(256) void k_mv2(
    const float* __restrict__ W2, const float* __restrict__ b2,
    const float* __restrict__ h, float* __restrict__ ks,
    float* __restrict__ y, float* __restrict__ yi,
    int stage, float dt)
{
    __shared__ float4 hlds[H / 4];
    const int tid = threadIdx.x;
    const float4* h4 = (const float4*)h;
    for (int i = tid; i < H / 4; i += 256) hlds[i] = h4[i];
    __syncthreads();

    const int wave = tid >> 6, lane = tid & 63;
    const int row = blockIdx.x * 4 + wave;
    const float4* w4 = (const float4*)(W2 + (size_t)row * H);
    float a0 = 0.f, a1 = 0.f, a2 = 0.f, a3 = 0.f;
    #pragma unroll
    for (int it = 0; it < H / 256; it += 4) {
        float4 w0 = w4[(it + 0) * 64 + lane], v0 = hlds[(it + 0) * 64 + lane];
        float4 w1 = w4[(it + 1) * 64 + lane], v1 = hlds[(it + 1) * 64 + lane];
        float4 w2 = w4[(it + 2) * 64 + lane], v2 = hlds[(it + 2) * 64 + lane];
        float4 w3 = w4[(it + 3) * 64 + lane], v3 = hlds[(it + 3) * 64 + lane];
        a0 = fmaf(w0.x, v0.x, a0); a0 = fmaf(w0.y, v0.y, a0);
        a0 = fmaf(w0.z, v0.z, a0); a0 = fmaf(w0.w, v0.w, a0);
        a1 = fmaf(w1.x, v1.x, a1); a1 = fmaf(w1.y, v1.y, a1);
        a1 = fmaf(w1.z, v1.z, a1); a1 = fmaf(w1.w, v1.w, a1);
        a2 = fmaf(w2.x, v2.x, a2); a2 = fmaf(w2.y, v2.y, a2);
        a2 = fmaf(w2.z, v2.z, a2); a2 = fmaf(w2.w, v2.w, a2);
        a3 = fmaf(w3.x, v3.x, a3); a3 = fmaf(w3.y, v3.y, a3);
        a3 = fmaf(w3.z, v3.z, a3); a3 = fmaf(w3.w, v3.w, a3);
    }
    float acc = waveReduce((a0 + a1) + (a2 + a3));
    if (lane == 0) {
        const float k = -(acc + b2[row]);
        ks[stage * D + row] = k;
        if (stage < 5) {
            float v = y[row];
            for (int j = 0; j < stage; ++j)
                v = fmaf(dt * c_A[stage + 1][j], ks[j * D + row], v);
            v = fmaf(dt * c_A[stage + 1][stage], k, v);
            yi[row] = v;
        } else {
            constexpr float B0 = 35.f/384.f, B2 = 500.f/1113.f, B3 = 125.f/192.f,
                            B4 = -2187.f/6784.f, B5 = 11.f/84.f;
            float sum = B0 * ks[0 * D + row];
            sum = fmaf(B2, ks[2 * D + row], sum);
            sum = fmaf(B3, ks[3 * D + row], sum);
            sum = fmaf(B4, ks[4 * D + row], sum);
            sum = fmaf(B5, k, sum);
            y[row] = fmaf(dt, sum, y[row]);  // in-place: each row owned by one wave
        }
    }
}

extern "C" void kernel_launch(void* const* d_in, const int* in_sizes, int n_in,
                              void* d_out, int out_size, void* d_ws, size_t ws_size,
                              hipStream_t stream) {
    const float* x  = (const float*)d_in[0];
    const float* W1 = (const float*)d_in[1];
    const float* wt = (const float*)d_in[2];
    const float* b1 = (const float*)d_in[3];
    const float* W2 = (const float*)d_in[4];
    const float* b2 = (const float*)d_in[5];
    float* out = (float*)d_out;

    float* ws = (float*)d_ws;
    float* y  = ws;              // [D]   current state
    float* yi = ws + D;          // [D]   stage input
    float* h  = ws + 2 * D;      // [H]   hidden activations
    float* ks = ws + 2 * D + H;  // [6*D] stage derivatives

    // y = x  (ws is re-poisoned before every timed call)
    hipMemcpyAsync(y, x, D * sizeof(float), hipMemcpyDeviceToDevice, stream);

    const float dt = 1.0f / 64.0f;
    const float C[6] = {0.f, 0.2f, 0.3f, 0.8f, 8.f/9.f, 1.f};

    for (int step = 0; step < NSTEPS; ++step) {
        const float t = (float)step * dt;
        for (int st = 0; st < 6; ++st) {
            const float s = 1.0f - (t + C[st] * dt);   // reversed-time argument
            const float* yin = (st == 0) ? y : yi;
            hipLaunchKernelGGL(k_mv1, dim3(H / 8), dim3(256), 0, stream,
                               W1, wt, b1, yin, h, s);
            hipLaunchKernelGGL(k_mv2, dim3(D / 4), dim3(256), 0, stream,
                               W2, b2, h, ks, y, yi, st, dt);
        }
    }

    hipMemcpyAsync(out, y, D * sizeof(float), hipMemcpyDeviceToDevice, stream);
}

// Round 2
// 6395.433 us; speedup vs baseline: 1.4768x; 1.4768x over previous
//
#include <hip/hip_runtime.h>
#include <hip/hip_fp16.h>

// Neural ODE (Dopri5, 64 steps) — D=2048 state, H=8192 hidden.
// Round 2: weights converted to fp16 in d_ws once per call (halves the
// dominant streaming traffic 49.2 GB -> 24.6 GB). Column-permuted fp16
// layout so LDS vector reads are conflict-free. fp32 state/accumulate.
// Fallback to fp32 path if ws_size too small.

constexpr int D = 2048;
constexpr int H = 8192;
constexpr int NSTEPS = 64;

__constant__ float c_A[6][5] = {
    {0.f, 0.f, 0.f, 0.f, 0.f},
    {1.f/5.f, 0.f, 0.f, 0.f, 0.f},
    {3.f/40.f, 9.f/40.f, 0.f, 0.f, 0.f},
    {44.f/45.f, -56.f/15.f, 32.f/9.f, 0.f, 0.f},
    {19372.f/6561.f, -25360.f/2187.f, 64448.f/6561.f, -212.f/729.f, 0.f},
    {9017.f/3168.f, -355.f/33.f, 46732.f/5247.f, 49.f/176.f, -5103.f/18656.f},
};

__device__ __forceinline__ float waveReduce(float v) {
    #pragma unroll
    for (int off = 32; off; off >>= 1) v += __shfl_down(v, off, 64);
    return v;
}

// ---------------------------------------------------------------------------
// fp32 -> fp16 conversion with column permutation.
// Chunk cp (8 halves, 16 B) of a row holds source float4 entries
// e0 = (cp>>6)*128 + (cp&63) and e1 = e0 + 64. At matvec time, lane l's
// chunk (it*64+l) then needs LDS float4 entries it*128+l and it*128+64+l:
// unit-stride across lanes -> conflict-free ds_read_b128.
// ---------------------------------------------------------------------------
struct alignas(16) H8 { __half2 a, b, c, d; };

__global__ __launch_bounds__(256) void k_conv(
    const float* __restrict__ src, float4* __restrict__ dst,
    int total /* rows * chunksPerRow */, int cprShift /* log2 chunksPerRow */)
{
    const float4* s4 = (const float4*)src;
    const int cpr = 1 << cprShift;
    const int epr = cpr * 2;  // float4 entries per row
    for (int g = blockIdx.x * 256 + threadIdx.x; g < total; g += gridDim.x * 256) {
        const int row = g >> cprShift;
        const int cp  = g & (cpr - 1);
        const int e0  = ((cp >> 6) << 7) | (cp & 63);
        float4 f0 = s4[(size_t)row * epr + e0];
        float4 f1 = s4[(size_t)row * epr + e0 + 64];
        H8 o;
        o.a = __floats2half2_rn(f0.x, f0.y);
        o.b = __floats2half2_rn(f0.z, f0.w);
        o.c = __floats2half2_rn(f1.x, f1.y);
        o.d = __floats2half2_rn(f1.z, f1.w);
        dst[g] = *(const float4*)&o;
    }
}

// ---------------------------------------------------------------------------
// fp16 matvec kernels
// ---------------------------------------------------------------------------

// h[row] = tanh( dot(W1[row,:], yi) + s*wt[row] + b1[row] )
// grid = H/8 = 1024 blocks x 256 thr (4 waves); wave -> 2 rows.
__global__ __launch_bounds__(256) void k_mv1_h(
    const float4* __restrict__ W1h,  // [H][256] 16B chunks, column-permuted
    const float* __restrict__ wt, const float* __restrict__ b1,
    const float* __restrict__ yi, float* __restrict__ h, float s)
{
    __shared__ float4 ylds[D / 4];
    const int tid = threadIdx.x;
    const float4* y4 = (const float4*)yi;
    for (int i = tid; i < D / 4; i += 256) ylds[i] = y4[i];
    __syncthreads();

    const int wave = tid >> 6, lane = tid & 63;
    const int row0 = blockIdx.x * 8 + wave * 2;
    const float4* w0 = W1h + (size_t)row0 * 256;
    const float4* w1 = w0 + 256;
    float a0 = 0.f, a1 = 0.f;
    #pragma unroll
    for (int it = 0; it < 4; ++it) {
        const int idx = it * 64 + lane;
        float4 p0 = w0[idx];
        float4 p1 = w1[idx];
        float4 va = ylds[it * 128 + lane];
        float4 vb = ylds[it * 128 + 64 + lane];
        const __half2* q0 = (const __half2*)&p0;
        const __half2* q1 = (const __half2*)&p1;
        float2 f;
        f = __half22float2(q0[0]); a0 = fmaf(f.x, va.x, fmaf(f.y, va.y, a0));
        f = __half22float2(q0[1]); a0 = fmaf(f.x, va.z, fmaf(f.y, va.w, a0));
        f = __half22float2(q0[2]); a0 = fmaf(f.x, vb.x, fmaf(f.y, vb.y, a0));
        f = __half22float2(q0[3]); a0 = fmaf(f.x, vb.z, fmaf(f.y, vb.w, a0));
        f = __half22float2(q1[0]); a1 = fmaf(f.x, va.x, fmaf(f.y, va.y, a1));
        f = __half22float2(q1[1]); a1 = fmaf(f.x, va.z, fmaf(f.y, va.w, a1));
        f = __half22float2(q1[2]); a1 = fmaf(f.x, vb.x, fmaf(f.y, vb.y, a1));
        f = __half22float2(q1[3]); a1 = fmaf(f.x, vb.z, fmaf(f.y, vb.w, a1));
    }
    a0 = waveReduce(a0);
    a1 = waveReduce(a1);
    if (lane == 0) {
        h[row0]     = tanhf(fmaf(s, wt[row0],     a0 + b1[row0]));
        h[row0 + 1] = tanhf(fmaf(s, wt[row0 + 1], a1 + b1[row0 + 1]));
    }
}

// k[row] = -( dot(W2[row,:], h) + b2[row] ) + fused tableau epilogue.
// grid = D/4 = 512 blocks x 256 thr (4 waves); wave -> 1 row.
__global__ __launch_bounds__(256) void k_mv2_h(
    const float4* __restrict__ W2h,  // [D][1024] 16B chunks, column-permuted
    const float* __restrict__ b2, const float* __restrict__ h,
    float* __restrict__ ks, float* __restrict__ y, float* __restrict__ yi,
    int stage, float dt)
{
    __shared__ float4 hlds[H / 4];
    const int tid = threadIdx.x;
    const float4* h4 = (const float4*)h;
    for (int i = tid; i < H / 4; i += 256) hlds[i] = h4[i];
    __syncthreads();

    const int wave = tid >> 6, lane = tid & 63;
    const int row = blockIdx.x * 4 + wave;
    const float4* w = W2h + (size_t)row * 1024;
    float a0 = 0.f, a1 = 0.f, a2 = 0.f, a3 = 0.f;
    #pragma unroll
    for (int it = 0; it < 16; it += 2) {
        const int i0 = it * 64 + lane;
        float4 p0 = w[i0];
        float4 p1 = w[i0 + 64];
        float4 va0 = hlds[it * 128 + lane];
        float4 vb0 = hlds[it * 128 + 64 + lane];
        float4 va1 = hlds[it * 128 + 128 + lane];
        float4 vb1 = hlds[it * 128 + 192 + lane];
        const __half2* q0 = (const __half2*)&p0;
        const __half2* q1 = (const __half2*)&p1;
        float2 f;
        f = __half22float2(q0[0]); a0 = fmaf(f.x, va0.x, fmaf(f.y, va0.y, a0));
        f = __half22float2(q0[1]); a0 = fmaf(f.x, va0.z, fmaf(f.y, va0.w, a0));
        f = __half22float2(q0[2]); a1 = fmaf(f.x, vb0.x, fmaf(f.y, vb0.y, a1));
        f = __half22float2(q0[3]); a1 = fmaf(f.x, vb0.z, fmaf(f.y, vb0.w, a1));
        f = __half22float2(q1[0]); a2 = fmaf(f.x, va1.x, fmaf(f.y, va1.y, a2));
        f = __half22float2(q1[1]); a2 = fmaf(f.x, va1.z, fmaf(f.y, va1.w, a2));
        f = __half22float2(q1[2]); a3 = fmaf(f.x, vb1.x, fmaf(f.y, vb1.y, a3));
        f = __half22float2(q1[3]); a3 = fmaf(f.x, vb1.z, fmaf(f.y, vb1.w, a3));
    }
    float acc = waveReduce((a0 + a1) + (a2 + a3));
    if (lane == 0) {
        const float k = -(acc + b2[row]);
        ks[stage * D + row] = k;
        if (stage < 5) {
            float v = y[row];
            for (int j = 0; j < stage; ++j)
                v = fmaf(dt * c_A[stage + 1][j], ks[j * D + row], v);
            v = fmaf(dt * c_A[stage + 1][stage], k, v);
            yi[row] = v;
        } else {
            constexpr float B0 = 35.f/384.f, B2 = 500.f/1113.f, B3 = 125.f/192.f,
                            B4 = -2187.f/6784.f, B5 = 11.f/84.f;
            float sum = B0 * ks[0 * D + row];
            sum = fmaf(B2, ks[2 * D + row], sum);
            sum = fmaf(B3, ks[3 * D + row], sum);
            sum = fmaf(B4, ks[4 * D + row], sum);
            sum = fmaf(B5, k, sum);
            y[row] = fmaf(dt, sum, y[row]);
        }
    }
}

// ---------------------------------------------------------------------------
// fp32 fallback matvec kernels (round-1, proven absmax 0.0)
// ---------------------------------------------------------------------------
__global__ __launch_bounds__(256) void k_mv1_f(
    const float* __restrict__ W1, const float* __restrict__ wt,
    const float* __restrict__ b1, const float* __restrict__ yi,
    float* __restrict__ h, float s)
{
    __shared__ float4 ylds[D / 4];
    const int tid = threadIdx.x;
    const float4* y4 = (const float4*)yi;
    for (int i = tid; i < D / 4; i += 256) ylds[i] = y4[i];
    __syncthreads();
    const int wave = tid >> 6, lane = tid & 63;
    const int rowBase = blockIdx.x * 8;
    #pragma unroll
    for (int rr = 0; rr < 2; ++rr) {
        const int row = rowBase + wave * 2 + rr;
        const float4* w4 = (const float4*)(W1 + (size_t)row * D);
        float a0 = 0.f, a1 = 0.f;
        #pragma unroll
        for (int it = 0; it < D / 256; it += 2) {
            float4 w0 = w4[(it + 0) * 64 + lane];
            float4 v0 = ylds[(it + 0) * 64 + lane];
            float4 w1 = w4[(it + 1) * 64 + lane];
            float4 v1 = ylds[(it + 1) * 64 + lane];
            a0 = fmaf(w0.x, v0.x, a0); a0 = fmaf(w0.y, v0.y, a0);
            a0 = fmaf(w0.z, v0.z, a0); a0 = fmaf(w0.w, v0.w, a0);
            a1 = fmaf(w1.x, v1.x, a1); a1 = fmaf(w1.y, v1.y, a1);
            a1 = fmaf(w1.z, v1.z, a1); a1 = fmaf(w1.w, v1.w, a1);
        }
        float acc = waveReduce(a0 + a1);
        if (lane == 0) h[row] = tanhf(fmaf(s, wt[row], acc + b1[row]));
    }
}

__global__ __launch_bounds__(256) void k_mv2_f(
    const float* __restrict__ W2, const float* __restrict__ b2,
    const float* __restrict__ h, float* __restrict__ ks,
    float* __restrict__ y, float* __restrict__ yi,
    int stage, float dt)
{
    __shared__ float4 hlds[H / 4];
    const int tid = threadIdx.x;
    const float4* h4 = (const float4*)h;
    for (int i = tid; i < H / 4; i += 256) hlds[i] = h4[i];
    __syncthreads();
    const int wave = tid >> 6, lane = tid & 63;
    const int row = blockIdx.x * 4 + wave;
    const float4* w4 = (const float4*)(W2 + (size_t)row * H);
    float a0 = 0.f, a1 = 0.f, a2 = 0.f, a3 = 0.f;
    #pragma unroll
    for (int it = 0; it < H / 256; it += 4) {
        float4 w0 = w4[(it + 0) * 64 + lane], v0 = hlds[(it + 0) * 64 + lane];
        float4 w1 = w4[(it + 1) * 64 + lane], v1 = hlds[(it + 1) * 64 + lane];
        float4 w2 = w4[(it + 2) * 64 + lane], v2 = hlds[(it + 2) * 64 + lane];
        float4 w3 = w4[(it + 3) * 64 + lane], v3 = hlds[(it + 3) * 64 + lane];
        a0 = fmaf(w0.x, v0.x, a0); a0 = fmaf(w0.y, v0.y, a0);
        a0 = fmaf(w0.z, v0.z, a0); a0 = fmaf(w0.w, v0.w, a0);
        a1 = fmaf(w1.x, v1.x, a1); a1 = fmaf(w1.y, v1.y, a1);
        a1 = fmaf(w1.z, v1.z, a1); a1 = fmaf(w1.w, v1.w, a1);
        a2 = fmaf(w2.x, v2.x, a2); a2 = fmaf(w2.y, v2.y, a2);
        a2 = fmaf(w2.z, v2.z, a2); a2 = fmaf(w2.w, v2.w, a2);
        a3 = fmaf(w3.x, v3.x, a3); a3 = fmaf(w3.y, v3.y, a3);
        a3 = fmaf(w3.z, v3.z, a3); a3 = fmaf(w3.w, v3.w, a3);
    }
    float acc = waveReduce((a0 + a1) + (a2 + a3));
    if (lane == 0) {
        const float k = -(acc + b2[row]);
        ks[stage * D + row] = k;
        if (stage < 5) {
            float v = y[row];
            for (int j = 0; j < stage; ++j)
                v = fmaf(dt * c_A[stage + 1][j], ks[j * D + row], v);
            v = fmaf(dt * c_A[stage + 1][stage], k, v);
            yi[row] = v;
        } else {
            constexpr float B0 = 35.f/384.f, B2 = 500.f/1113.f, B3 = 125.f/192.f,
                            B4 = -2187.f/6784.f, B5 = 11.f/84.f;
            float sum = B0 * ks[0 * D + row];
            sum = fmaf(B2, ks[2 * D + row], sum);
            sum = fmaf(B3, ks[3 * D + row], sum);
            sum = fmaf(B4, ks[4 * D + row], sum);
            sum = fmaf(B5, k, sum);
            y[row] = fmaf(dt, sum, y[row]);
        }
    }
}

extern "C" void kernel_launch(void* const* d_in, const int* in_sizes, int n_in,
                              void* d_out, int out_size, void* d_ws, size_t ws_size,
                              hipStream_t stream) {
    const float* x  = (const float*)d_in[0];
    const float* W1 = (const float*)d_in[1];
    const float* wt = (const float*)d_in[2];
    const float* b1 = (const float*)d_in[3];
    const float* W2 = (const float*)d_in[4];
    const float* b2 = (const float*)d_in[5];
    float* out = (float*)d_out;

    float* ws = (float*)d_ws;
    float* y  = ws;              // [D]
    float* yi = ws + D;          // [D]
    float* h  = ws + 2 * D;      // [H]
    float* ks = ws + 2 * D + H;  // [6*D]
    constexpr size_t VEC_FLOATS = 2 * D + H + 6 * D;           // 24576
    float4* W1h = (float4*)(ws + VEC_FLOATS);                  // H*D halves
    float4* W2h = (float4*)((__half*)W1h + (size_t)H * D);     // D*H halves
    const size_t need = VEC_FLOATS * 4 + (size_t)2 * H * D * 2;
    const bool f16 = ws_size >= need;

    hipMemcpyAsync(y, x, D * sizeof(float), hipMemcpyDeviceToDevice, stream);

    const float dt = 1.0f / 64.0f;
    const float C[6] = {0.f, 0.2f, 0.3f, 0.8f, 8.f/9.f, 1.f};

    if (f16) {
        hipLaunchKernelGGL(k_conv, dim3(2048), dim3(256), 0, stream,
                           W1, W1h, H * (D / 8), 8 /* log2(2048/8) */);
        hipLaunchKernelGGL(k_conv, dim3(2048), dim3(256), 0, stream,
                           W2, W2h, D * (H / 8), 10 /* log2(8192/8) */);
    }

    for (int step = 0; step < NSTEPS; ++step) {
        const float t = (float)step * dt;
        for (int st = 0; st < 6; ++st) {
            const float s = 1.0f - (t + C[st] * dt);
            const float* yin = (st == 0) ? y : yi;
            if (f16) {
                hipLaunchKernelGGL(k_mv1_h, dim3(H / 8), dim3(256), 0, stream,
                                   W1h, wt, b1, yin, h, s);
                hipLaunchKernelGGL(k_mv2_h, dim3(D / 4), dim3(256), 0, stream,
                                   W2h, b2, h, ks, y, yi, st, dt);
            } else {
                hipLaunchKernelGGL(k_mv1_f, dim3(H / 8), dim3(256), 0, stream,
                                   W1, wt, b1, yin, h, s);
                hipLaunchKernelGGL(k_mv2_f, dim3(D / 4), dim3(256), 0, stream,
                                   W2, b2, h, ks, y, yi, st, dt);
            }
        }
    }

    hipMemcpyAsync(out, y, D * sizeof(float), hipMemcpyDeviceToDevice, stream);
}